// Round 7
// baseline (5920.222 us; speedup 1.0000x reference)
//
#include <hip/hip_runtime.h>
#include <math.h>

// B=32, D=256, T=1024, H=512, 4H=2048
// Two independent groups of 16 blocks; group owns 16 batches, block owns 32 h-cols.
// Wave layout: wave = (gate, khalf). Each wave: half of K, both 16-col tiles.
// THIS ROUND: consume phase deleted. h-part MFMA A-frags are fed DIRECTLY from
// hbuf (each lane's 16B frag for K-granule ks is contiguous in producer
// (8kh+ks)'s published row). No h_lds, no bulk-load wave, no B4 barrier.
// Step = flag gather-wait (8 flags in one vector load, ballot loop) -> 16
// pipelined hbuf loads -> 16 MFMAs -> gates -> B1 -> EW -> publish -> x-part
// -> drain -> barrier -> flag. 2 barriers/step instead of 4; two exchange
// latency legs (max-flag, data) instead of four.
// Protocol primitives identical to proven r0/r2 (relaxed agent atomics, flag
// monotone counters); numerics bit-identical (same bf16 values, same K order).
// ws: [0,16MB) xT bf16 [T][B][D]; +16MB flags (8KB); +8KB hbuf dw [2grp][2ph][16][256]

using short8  = __attribute__((ext_vector_type(8))) short;
using f32x4   = __attribute__((ext_vector_type(4))) float;
using float4v = __attribute__((ext_vector_type(4))) float;
using ull2    = __attribute__((ext_vector_type(2))) unsigned long long;

__device__ inline unsigned short f2bf(float f) {
    unsigned u = __float_as_uint(f);
    unsigned r = u + 0x7fffu + ((u >> 16) & 1u);
    return (unsigned short)(r >> 16);
}
__device__ inline float fsig(float x) {
    return __builtin_amdgcn_rcpf(1.0f + __expf(-x));
}
__device__ inline float ftanh(float x) {
    return 2.0f * __builtin_amdgcn_rcpf(1.0f + __expf(-2.0f * x)) - 1.0f;
}

__global__ void zero_ws(unsigned* p) {
    p[blockIdx.x * 256 + threadIdx.x] = 0u;
}

// ---------------- Phase 1: xT[t][b][d] = bf16(x[b][d][t]) ----------------
__global__ __launch_bounds__(256) void x_transpose(const float* __restrict__ x,
                                                   unsigned short* __restrict__ xT) {
    __shared__ unsigned short tile[64][65];
    const int tid = threadIdx.x;
    const int t0 = blockIdx.x * 64, d0 = blockIdx.y * 64, b = blockIdx.z;
    for (int p = 0; p < 16; p++) {
        int d = p * 4 + (tid >> 6);
        int t = tid & 63;
        tile[d][t] = f2bf(x[(b * 256 + d0 + d) * 1024 + t0 + t]);
    }
    __syncthreads();
    for (int p = 0; p < 16; p++) {
        int t = p * 4 + (tid >> 6);
        int d = tid & 63;
        xT[(size_t)(t0 + t) * 8192 + b * 256 + d0 + d] = tile[d][t];
    }
}

// ---------------- Phase 2: recurrence ----------------
#define GS 33    // gates_lds row stride (floats)
#define OS 17    // out_stage row stride (floats)

__global__ __launch_bounds__(512) void lstm_rec(const unsigned short* __restrict__ xT,
                                                const float* __restrict__ Wih,
                                                const float* __restrict__ Whh,
                                                const float* __restrict__ bih,
                                                const float* __restrict__ bhh,
                                                float* __restrict__ out,
                                                unsigned* flags,
                                                unsigned* hbuf) {
    __shared__ float gates_lds[8 * 16 * GS];                      // 16.9 KB (2 partials)
    __shared__ float out_stage[512 * OS];                         // 34.8 KB

    const int tid  = threadIdx.x;
    const int wave = tid >> 6;
    const int lane = tid & 63;
    const int quad = lane >> 4, l15 = lane & 15;
    const int group = blockIdx.x & 1;
    const int g     = blockIdx.x >> 1;         // h-slice [32g, 32g+32)
    const int gate  = wave >> 1;               // i,f,g,o
    const int kh    = wave & 1;                // K-half

    // one-time weight preload: 2 col-tiles x (8 h-ks + 4 x-ks), K-range = kh half
    short8 whh_frag[2][8];
    short8 wih_frag[2][4];
    float bias_t[2];
    for (int tile = 0; tile < 2; tile++) {
        const int nrow = gate * 512 + g * 32 + tile * 16 + l15;
        for (int ks = 0; ks < 8; ks++) {
            const float* p = &Whh[(size_t)nrow * 512 + kh * 256 + ks * 32 + quad * 8];
            short8 v;
            for (int j = 0; j < 8; j++) v[j] = (short)f2bf(p[j]);
            whh_frag[tile][ks] = v;
        }
        for (int ks = 0; ks < 4; ks++) {
            const float* p = &Wih[(size_t)nrow * 256 + kh * 128 + ks * 32 + quad * 8];
            short8 v;
            for (int j = 0; j < 8; j++) v[j] = (short)f2bf(p[j]);
            wih_frag[tile][ks] = v;
        }
        bias_t[tile] = (kh == 0) ? (bih[nrow] + bhh[nrow]) : 0.0f;
    }

    const int eb = tid >> 5, ek = tid & 31;    // elementwise: local batch, local col
    const int hidx = g * 32 + ek;

    // x A-fragment source for this lane: row = batch l15, K-chunk = kh/ks/quad
    const unsigned short* xbase = xT + (size_t)(group * 16 + l15) * 256 + kh * 128 + quad * 8;

    // prefetch x for t=0 into registers
    short8 xf[4];
#pragma unroll
    for (int ks = 0; ks < 4; ks++)
        xf[ks] = *(const short8*)(xbase + (size_t)0 * 8192 + ks * 32);

    float c = 0.0f;
    float* out_base = out + ((size_t)(group * 16 + eb) * 512 + hidx) * 1024;
    unsigned* my_flags = flags + group * 512;            // 16 flags, 128 B apart
    unsigned* hb_base  = hbuf + group * 8192;            // [2 phase][16 b][256 cp]

    // h A-frag source (ull units): + ph*2048 + ks*8 (+0/1) at use
    const unsigned long long* hrow_base =
        (const unsigned long long*)hb_base + (l15 * 128 + kh * 64 + quad * 2);
    // flag poll address: lanes 0..7 cover this wave's 8 producers
    const unsigned* fpoll = &my_flags[((kh << 3) + (lane & 7)) * 32];
    const bool poller = (lane < 8);

    __syncthreads();

    // t=0 x-part
    f32x4 acc0 = f32x4{bias_t[0], bias_t[0], bias_t[0], bias_t[0]};
    f32x4 acc1 = f32x4{bias_t[1], bias_t[1], bias_t[1], bias_t[1]};
#pragma unroll
    for (int ks = 0; ks < 4; ks++) {
        acc0 = __builtin_amdgcn_mfma_f32_16x16x32_bf16(xf[ks], wih_frag[0][ks], acc0, 0, 0, 0);
        acc1 = __builtin_amdgcn_mfma_f32_16x16x32_bf16(xf[ks], wih_frag[1][ks], acc1, 0, 0, 0);
    }

    for (int t = 0; t < 1024; t++) {
        // P0: issue x prefetch for t+1 into registers (latency hidden under step)
        if (t + 1 < 1024) {
#pragma unroll
            for (int ks = 0; ks < 4; ks++)
                xf[ks] = *(const short8*)(xbase + (size_t)(t + 1) * 8192 + ks * 32);
        }

        // ---- flag gather-wait: one vector load covers all 8 producers of this
        // wave's K-half; ballot loop exits when all have published h_{t-1} ----
        {
            unsigned fv;
            do {
                fv = poller ? __hip_atomic_load(fpoll, __ATOMIC_RELAXED,
                                                __HIP_MEMORY_SCOPE_AGENT)
                            : ~0u;
            } while (__ballot(fv >= (unsigned)t) != ~0ull);
        }
        __builtin_amdgcn_sched_barrier(0);

        // ---- h-part: 16 independent 8B loads straight from hbuf, then 16 MFMAs.
        // A-frag for (kh,ks,quad) = producer (8kh+ks)'s packed row — contiguous 16B.
        {
            const unsigned long long* hrow = hrow_base + ((t + 1) & 1) * 2048;
            unsigned long long u[16];
#pragma unroll
            for (int ks = 0; ks < 8; ks++) {
                u[2 * ks]     = __hip_atomic_load(hrow + (ks << 3),     __ATOMIC_RELAXED, __HIP_MEMORY_SCOPE_AGENT);
                u[2 * ks + 1] = __hip_atomic_load(hrow + (ks << 3) + 1, __ATOMIC_RELAXED, __HIP_MEMORY_SCOPE_AGENT);
            }
#pragma unroll
            for (int ks = 0; ks < 8; ks++) {
                ull2 uv;
                uv[0] = u[2 * ks];
                uv[1] = u[2 * ks + 1];
                short8 af = __builtin_bit_cast(short8, uv);
                acc0 = __builtin_amdgcn_mfma_f32_16x16x32_bf16(af, whh_frag[0][ks], acc0, 0, 0, 0);
                acc1 = __builtin_amdgcn_mfma_f32_16x16x32_bf16(af, whh_frag[1][ks], acc1, 0, 0, 0);
            }
        }

        // P2: write K-half partials
        {
            const int prow = (kh * 4 + gate) * 16;
#pragma unroll
            for (int r = 0; r < 4; r++) {
                gates_lds[(prow + quad * 4 + r) * GS + l15]      = acc0[r];
                gates_lds[(prow + quad * 4 + r) * GS + 16 + l15] = acc1[r];
            }
        }
        // B1: raw barrier, LDS drain only (x loads stay in flight)
        asm volatile("s_waitcnt lgkmcnt(0)" ::: "memory");
        __builtin_amdgcn_sched_barrier(0);
        __builtin_amdgcn_s_barrier();
        __builtin_amdgcn_sched_barrier(0);

        // P4: elementwise: sum K-half partials, gate math
        float iv = gates_lds[(0 * 16 + eb) * GS + ek] + gates_lds[(4 * 16 + eb) * GS + ek];
        float fv = gates_lds[(1 * 16 + eb) * GS + ek] + gates_lds[(5 * 16 + eb) * GS + ek];
        float gv = gates_lds[(2 * 16 + eb) * GS + ek] + gates_lds[(6 * 16 + eb) * GS + ek];
        float ov = gates_lds[(3 * 16 + eb) * GS + ek] + gates_lds[(7 * 16 + eb) * GS + ek];
        iv = fsig(iv); fv = fsig(fv); gv = ftanh(gv); ov = fsig(ov);
        c = fv * c + iv * gv;
        float h = ov * ftanh(c);

        // publish packed bf16x2 dwords (fire now, drain later)
        unsigned my = f2bf(h);
        unsigned nb = (unsigned)__shfl_xor((int)my, 1);
        if (t < 1023 && !(ek & 1)) {
            __hip_atomic_store(&hb_base[(t & 1) * 4096 + eb * 256 + g * 16 + (ek >> 1)],
                               my | (nb << 16), __ATOMIC_RELAXED, __HIP_MEMORY_SCOPE_AGENT);
        }

        out_stage[tid * OS + (t & 15)] = h;

        if (t == 1023) break;

        // ---- next step's x-part while publish stores drain ----
        acc0 = f32x4{bias_t[0], bias_t[0], bias_t[0], bias_t[0]};
        acc1 = f32x4{bias_t[1], bias_t[1], bias_t[1], bias_t[1]};
#pragma unroll
        for (int ks = 0; ks < 4; ks++) {
            acc0 = __builtin_amdgcn_mfma_f32_16x16x32_bf16(xf[ks], wih_frag[0][ks], acc0, 0, 0, 0);
            acc1 = __builtin_amdgcn_mfma_f32_16x16x32_bf16(xf[ks], wih_frag[1][ks], acc1, 0, 0, 0);
        }

        // ---- drain own publish stores, then flag (per-wave drain + barrier
        // guarantees whole block's stores are committed before tid0 flags) ----
        asm volatile("s_waitcnt vmcnt(0)" ::: "memory");
        __builtin_amdgcn_sched_barrier(0);
        __builtin_amdgcn_s_barrier();
        __builtin_amdgcn_sched_barrier(0);
        if (tid == 0)
            __hip_atomic_store(&my_flags[g * 32], (unsigned)(t + 1),
                               __ATOMIC_RELAXED, __HIP_MEMORY_SCOPE_AGENT);

        // out flush every 16 steps (own LDS row) — after flag, rides the next
        // step's flag-wait shadow; drained by next 16th-step vmcnt long after.
        if ((t & 15) == 15) {
            int t0 = t & ~15;
#pragma unroll
            for (int q = 0; q < 4; q++) {
                float4v v = *(const float4v*)&out_stage[tid * OS + q * 4];
                *(float4v*)&out_base[t0 + q * 4] = v;
            }
        }
    }

    // epilogue: flush last 16 outputs (t = 1008..1023)
#pragma unroll
    for (int q = 0; q < 4; q++) {
        float4v v = *(const float4v*)&out_stage[tid * OS + q * 4];
        *(float4v*)&out_base[1008 + q * 4] = v;
    }
}

extern "C" void kernel_launch(void* const* d_in, const int* in_sizes, int n_in,
                              void* d_out, int out_size, void* d_ws, size_t ws_size,
                              hipStream_t stream) {
    (void)in_sizes; (void)n_in; (void)out_size; (void)ws_size;
    const float* x   = (const float*)d_in[0];
    const float* Wih = (const float*)d_in[1];
    const float* Whh = (const float*)d_in[2];
    const float* bih = (const float*)d_in[3];
    const float* bhh = (const float*)d_in[4];
    float* out = (float*)d_out;

    char* ws = (char*)d_ws;
    unsigned short* xT = (unsigned short*)ws;                 // 16,777,216 B
    unsigned* flags    = (unsigned*)(ws + 16777216);          // 8 KB
    unsigned* hbuf     = (unsigned*)(ws + 16777216 + 8192);   // 64 KB

    // zero flags (8KB) + hbuf (64KB): consumers read hbuf phase-1 zeros at t=0
    zero_ws<<<72, 256, 0, stream>>>(flags);
    dim3 gT(16, 4, 32);
    x_transpose<<<gT, 256, 0, stream>>>(x, xT);
    lstm_rec<<<32, 512, 0, stream>>>(xT, Wih, Whh, bih, bhh, out, flags, hbuf);
}